// Round 1
// 3907.008 us; speedup vs baseline: 1.0220x; 1.0220x over previous
//
#include <hip/hip_runtime.h>
#include <stdint.h>

// GPT-2 small forward on gfx950. bf16 MFMA compute, fp32 residual stream.
#define NLAYER 12
#define NHEAD  12
#define CDIM   768
#define TSEQ   1024
#define BATCH  2
#define ROWS   (BATCH * TSEQ)      // 2048
#define VOCAB  50257
#define VPAD   50304               // multiple of 128

typedef __bf16 bf16_t;
typedef __attribute__((ext_vector_type(8))) __bf16 bf16x8;
typedef __attribute__((ext_vector_type(4))) float f32x4;

typedef __attribute__((address_space(1))) uint32_t gu32;
typedef __attribute__((address_space(3))) uint32_t lu32;

// async global->LDS, 16B per lane. LDS dest is wave-uniform base + lane*16.
__device__ __forceinline__ void gl2lds16(const void* g, void* lds) {
    __builtin_amdgcn_global_load_lds((gu32*)(uintptr_t)g, (lu32*)(uintptr_t)lds,
                                     16, 0, 0);
}

// ---------------------------------------------------------------- embedding
__global__ void embed_kernel(const int* __restrict__ idx,
                             const float* __restrict__ wte,
                             const float* __restrict__ wpe,
                             float* __restrict__ x) {
    const int row = blockIdx.x;            // b*1024 + t
    const int t = row & (TSEQ - 1);
    const int id = idx[row];
    const float* src = wte + (size_t)id * CDIM;
    const float* pe  = wpe + (size_t)t * CDIM;
    float* dst = x + (size_t)row * CDIM;
    for (int c = threadIdx.x; c < CDIM; c += 256) dst[c] = src[c] + pe[c];
}

// ---------------------------------------------------------------- layernorm
// one block (256 thr) per row; fp32 in, bf16 out
__global__ void ln_kernel(const float* __restrict__ x,
                          const float* __restrict__ g,
                          const float* __restrict__ b,
                          bf16_t* __restrict__ out) {
    const int row = blockIdx.x, tid = threadIdx.x;
    const float* xr = x + (size_t)row * CDIM;
    float v0 = xr[tid], v1 = xr[tid + 256], v2 = xr[tid + 512];
    __shared__ float sb[8];
    float s = v0 + v1 + v2;
#pragma unroll
    for (int o = 32; o > 0; o >>= 1) s += __shfl_down(s, o);
    if ((tid & 63) == 0) sb[tid >> 6] = s;
    __syncthreads();
    const float mean = (sb[0] + sb[1] + sb[2] + sb[3]) * (1.0f / CDIM);
    const float d0 = v0 - mean, d1 = v1 - mean, d2 = v2 - mean;
    float q = d0 * d0 + d1 * d1 + d2 * d2;
#pragma unroll
    for (int o = 32; o > 0; o >>= 1) q += __shfl_down(q, o);
    if ((tid & 63) == 0) sb[4 + (tid >> 6)] = q;
    __syncthreads();
    const float var = (sb[4] + sb[5] + sb[6] + sb[7]) * (1.0f / CDIM);
    const float rs = rsqrtf(var + 1e-5f);
    bf16_t* orow = out + (size_t)row * CDIM;
    orow[tid]       = (bf16_t)(d0 * rs * g[tid]       + b[tid]);
    orow[tid + 256] = (bf16_t)(d1 * rs * g[tid + 256] + b[tid + 256]);
    orow[tid + 512] = (bf16_t)(d2 * rs * g[tid + 512] + b[tid + 512]);
}

// ----------------------------------------------- fp32 [K,N] -> bf16 [Ngrid,K]
// transpose + convert. Reads guard n < Ncols (pad rows get 0). block (32,8).
// (retained for lm_w only; per-layer weights use transpose_layer below)
__global__ void transpose_cvt(const float* __restrict__ in,
                              bf16_t* __restrict__ out,
                              int Krows, int Ncols) {
    __shared__ bf16_t tile[32][33];
    const int tx = threadIdx.x, ty = threadIdx.y;
    const int n0 = blockIdx.x * 32, k0 = blockIdx.y * 32;
#pragma unroll
    for (int i = 0; i < 4; i++) {
        int k = k0 + ty + i * 8, n = n0 + tx;
        float v = (n < Ncols) ? in[(size_t)k * Ncols + n] : 0.0f;
        tile[ty + i * 8][tx] = (bf16_t)v;
    }
    __syncthreads();
#pragma unroll
    for (int i = 0; i < 4; i++) {
        int n = n0 + ty + i * 8, k = k0 + tx;
        out[(size_t)n * Krows + k] = tile[tx][ty + i * 8];
    }
}

// -------------------------------- all 4 weight transposes of one layer, fused
// One launch replaces 4 serialized small kernels: 6912 blocks of (32,8).
//   seg0 [0,1728):    wqkv  [768,2304]  -> qkvT  [2304,768]   (72 x 24)
//   seg1 [1728,2304): wproj [768,768]   -> projT [768,768]    (24 x 24)
//   seg2 [2304,4608): wfc   [768,3072]  -> fcT   [3072,768]   (96 x 24)
//   seg3 [4608,6912): wfc2  [3072,768]  -> fc2T  [768,3072]   (24 x 96)
// All dims are multiples of 32 -> no column guard needed.
__global__ void transpose_layer(const float* __restrict__ wqkv,
                                const float* __restrict__ wproj,
                                const float* __restrict__ wfc,
                                const float* __restrict__ wfc2,
                                bf16_t* __restrict__ qkvT,
                                bf16_t* __restrict__ projT,
                                bf16_t* __restrict__ fcT,
                                bf16_t* __restrict__ fc2T) {
    __shared__ bf16_t tile[32][33];
    int id = blockIdx.x;
    const float* src;
    bf16_t* dst;
    int Krows, Ncols, bx, by;
    if (id < 1728) {
        src = wqkv;  dst = qkvT;  Krows = 768;  Ncols = 2304;
        bx = id % 72; by = id / 72;
    } else if (id < 2304) {
        id -= 1728;
        src = wproj; dst = projT; Krows = 768;  Ncols = 768;
        bx = id % 24; by = id / 24;
    } else if (id < 4608) {
        id -= 2304;
        src = wfc;   dst = fcT;   Krows = 768;  Ncols = 3072;
        bx = id % 96; by = id / 96;
    } else {
        id -= 4608;
        src = wfc2;  dst = fc2T;  Krows = 3072; Ncols = 768;
        bx = id % 24; by = id / 24;
    }
    const int tx = threadIdx.x, ty = threadIdx.y;
    const int n0 = bx * 32, k0 = by * 32;
#pragma unroll
    for (int i = 0; i < 4; i++) {
        int k = k0 + ty + i * 8, n = n0 + tx;
        tile[ty + i * 8][tx] = (bf16_t)src[(size_t)k * Ncols + n];
    }
    __syncthreads();
#pragma unroll
    for (int i = 0; i < 4; i++) {
        int n = n0 + ty + i * 8, k = k0 + tx;
        dst[(size_t)n * Krows + k] = tile[tx][ty + i * 8];
    }
}

// ------------------------------------- V slice of qkv -> vT [B*H*64, 1024]
__global__ void vtrans_kernel(const bf16_t* __restrict__ qkv,
                              bf16_t* __restrict__ vT) {
    __shared__ bf16_t tile[32][33];
    const int tx = threadIdx.x, ty = threadIdx.y;
    const int t0 = blockIdx.x * 32, d0 = blockIdx.y * 32, bh = blockIdx.z;
    const int b = bh / NHEAD, hh = bh % NHEAD;
#pragma unroll
    for (int i = 0; i < 4; i++) {
        int t = t0 + ty + i * 8;
        tile[ty + i * 8][tx] =
            qkv[(size_t)(b * TSEQ + t) * (3 * CDIM) + 2 * CDIM + hh * 64 + d0 + tx];
    }
    __syncthreads();
#pragma unroll
    for (int i = 0; i < 4; i++) {
        int d = d0 + ty + i * 8;
        vT[(size_t)(bh * 64 + d) * TSEQ + t0 + tx] = tile[tx][ty + i * 8];
    }
}

// ---------------------------------------------------------- flash attention
// grid (T/64, H, B), 256 thr. Wave w handles 16 q rows; no cross-wave sync.
__global__ __launch_bounds__(256) void attn_kernel(const bf16_t* __restrict__ qkv,
                                                   const bf16_t* __restrict__ vT,
                                                   bf16_t* __restrict__ y) {
    const int w = threadIdx.x >> 6, l = threadIdx.x & 63;
    const int lr = l & 15, lq = l >> 4;
    const int qt = blockIdx.x, hh = blockIdx.y, b = blockIdx.z;
    const int q0 = qt * 64 + w * 16;

    __shared__ __align__(16) bf16_t plds[4][16 * 40];  // padded P tiles
    bf16_t* myp = &plds[w][0];

    // Q fragments (A-layout): row=lr, k = lq*8 + j (+32)
    const bf16_t* qb = qkv + (size_t)(b * TSEQ + q0 + lr) * (3 * CDIM) + hh * 64 + lq * 8;
    const bf16x8 aq0 = *(const bf16x8*)qb;
    const bf16x8 aq1 = *(const bf16x8*)(qb + 32);

    const bf16_t* kbase = qkv + (size_t)(b * TSEQ + lr) * (3 * CDIM) + CDIM + hh * 64 + lq * 8;
    const bf16_t* vbase = vT + (size_t)((b * NHEAD + hh) * 64 + lr) * TSEQ + lq * 8;

    float mrow[4], srow[4];
    f32x4 o[4];
#pragma unroll
    for (int r = 0; r < 4; r++) { mrow[r] = -1e30f; srow[r] = 0.0f; }
#pragma unroll
    for (int db = 0; db < 4; db++) o[db] = (f32x4){0.f, 0.f, 0.f, 0.f};

    const int kbmax = (q0 + 15) >> 5;
    for (int kb = 0; kb <= kbmax; kb++) {
        f32x4 st[2];
#pragma unroll
        for (int n16 = 0; n16 < 2; n16++) {
            const bf16_t* kp = kbase + (size_t)(kb * 32 + n16 * 16) * (3 * CDIM);
            bf16x8 bk0 = *(const bf16x8*)kp;
            bf16x8 bk1 = *(const bf16x8*)(kp + 32);
            f32x4 acc = (f32x4){0.f, 0.f, 0.f, 0.f};
            acc = __builtin_amdgcn_mfma_f32_16x16x32_bf16(aq0, bk0, acc, 0, 0, 0);
            acc = __builtin_amdgcn_mfma_f32_16x16x32_bf16(aq1, bk1, acc, 0, 0, 0);
            st[n16] = acc;
        }
#pragma unroll
        for (int r = 0; r < 4; r++) {
            const int qrow = q0 + lq * 4 + r;
            float v0 = st[0][r] * 0.125f;
            float v1 = st[1][r] * 0.125f;
            if (kb * 32 + lr > qrow) v0 = -1e30f;
            if (kb * 32 + 16 + lr > qrow) v1 = -1e30f;
            float mx = fmaxf(v0, v1);
#pragma unroll
            for (int d = 1; d < 16; d <<= 1) mx = fmaxf(mx, __shfl_xor(mx, d));
            const float mnew = fmaxf(mrow[r], mx);
            const float alpha = __expf(mrow[r] - mnew);
            mrow[r] = mnew;
            const float p0 = __expf(v0 - mnew);
            const float p1 = __expf(v1 - mnew);
            float rsum = p0 + p1;
#pragma unroll
            for (int d = 1; d < 16; d <<= 1) rsum += __shfl_xor(rsum, d);
            srow[r] = srow[r] * alpha + rsum;
#pragma unroll
            for (int db = 0; db < 4; db++) o[db][r] *= alpha;
            myp[(lq * 4 + r) * 40 + lr]      = (bf16_t)p0;
            myp[(lq * 4 + r) * 40 + 16 + lr] = (bf16_t)p1;
        }
        // P in A-layout: row=lr, k=lq*8+j   (compiler inserts lgkmcnt wait)
        const bf16x8 ap = *(const bf16x8*)(myp + lr * 40 + lq * 8);
        const bf16_t* vb = vbase + kb * 32;
#pragma unroll
        for (int db = 0; db < 4; db++) {
            bf16x8 bv = *(const bf16x8*)(vb + (size_t)db * 16 * TSEQ);
            o[db] = __builtin_amdgcn_mfma_f32_16x16x32_bf16(ap, bv, o[db], 0, 0, 0);
        }
    }
#pragma unroll
    for (int db = 0; db < 4; db++)
#pragma unroll
        for (int r = 0; r < 4; r++) {
            const float val = o[db][r] / srow[r];
            y[(size_t)(b * TSEQ + q0 + lq * 4 + r) * CDIM + hh * 64 + db * 16 + lr] =
                (bf16_t)val;
        }
}

// -------------------------------------------------------------------- GEMM
// C[M,N] = A[M,K] * Bt[N,K]^T  (+bias, +res, gelu per EPI), m97 structure.
// EPI: 0 = bias -> bf16 out; 1 = bias + res -> f32 out (residual add);
//      2 = bias + gelu -> bf16 out; 3 = plain -> f32 out, col-guarded (Nout).
// EPI==3 (LM head, grid 393x16=6288 wg): XCD-chunked m-fastest block remap.
//   HW round-robins linear wg id across 8 XCDs; orig=(lin&7)*786+(lin>>3)
//   gives each XCD a contiguous chunk of n-tiles with m fastest -> each
//   196KB B-panel is read by its 16 m-blocks on ONE XCD (L2-hit), B fetched
//   ~once from HBM instead of ~8x. Bijective since 6288%8==0 (ERRATA #11).
template <int EPI>
__global__ __launch_bounds__(256) void gemm_bt(const bf16_t* __restrict__ A,
                                               const bf16_t* __restrict__ Bt,
                                               const float* __restrict__ bias,
                                               const float* res, void* outp,
                                               int K, int Nout) {
    __shared__ __align__(16) bf16_t As[128 * 32];
    __shared__ __align__(16) bf16_t Bs[128 * 32];
    const int tid = threadIdx.x;
    const int w = tid >> 6, l = tid & 63;
    const int lr = l & 15, lq = l >> 4;
    const int wm = w >> 1, wn = w & 1;

    int n_t, m_t;
    if (EPI == 3) {
        const unsigned lin = blockIdx.y * gridDim.x + blockIdx.x;
        const unsigned nwg = gridDim.x * gridDim.y;          // 6288, %8==0
        const unsigned orig = (lin & 7u) * (nwg >> 3) + (lin >> 3);
        m_t = orig & 15u;                                    // gridDim.y == 16
        n_t = orig >> 4;
    } else {
        n_t = blockIdx.x; m_t = blockIdx.y;
    }
    const int n0 = n_t * 128, m0 = m_t * 128;

    const bf16_t* ga = A + (size_t)(m0 + w * 16 + (l >> 2)) * K + (l & 3) * 8;
    const bf16_t* gb = Bt + (size_t)(n0 + w * 16 + (l >> 2)) * K + (l & 3) * 8;
    char* la = (char*)As + w * 1024;
    char* lb = (char*)Bs + w * 1024;
    const size_t stride64 = (size_t)64 * K;

    f32x4 acc[4][4];
#pragma unroll
    for (int i = 0; i < 4; i++)
#pragma unroll
        for (int j = 0; j < 4; j++) acc[i][j] = (f32x4){0.f, 0.f, 0.f, 0.f};

    for (int k0 = 0; k0 < K; k0 += 32) {
        gl2lds16(ga, la);
        gl2lds16(ga + stride64, la + 4096);
        gl2lds16(gb, lb);
        gl2lds16(gb + stride64, lb + 4096);
        ga += 32; gb += 32;
        __syncthreads();
        bf16x8 af[4], bfr[4];
#pragma unroll
        for (int i = 0; i < 4; i++)
            af[i] = *(const bf16x8*)((const char*)As + (wm * 64 + i * 16 + lr) * 64 + lq * 16);
#pragma unroll
        for (int j = 0; j < 4; j++)
            bfr[j] = *(const bf16x8*)((const char*)Bs + (wn * 64 + j * 16 + lr) * 64 + lq * 16);
#pragma unroll
        for (int i = 0; i < 4; i++)
#pragma unroll
            for (int j = 0; j < 4; j++)
                acc[i][j] = __builtin_amdgcn_mfma_f32_16x16x32_bf16(af[i], bfr[j],
                                                                   acc[i][j], 0, 0, 0);
        __syncthreads();
    }

    float bj[4];
    if (EPI != 3) {
#pragma unroll
        for (int j = 0; j < 4; j++) bj[j] = bias[n0 + wn * 64 + j * 16 + lr];
    }
#pragma unroll
    for (int i = 0; i < 4; i++) {
#pragma unroll
        for (int r = 0; r < 4; r++) {
            const size_t m = m0 + wm * 64 + i * 16 + lq * 4 + r;
#pragma unroll
            for (int j = 0; j < 4; j++) {
                const int n = n0 + wn * 64 + j * 16 + lr;
                float v = acc[i][j][r];
                if (EPI != 3) v += bj[j];
                if (EPI == 0) {
                    ((bf16_t*)outp)[m * Nout + n] = (bf16_t)v;
                } else if (EPI == 1) {
                    float* po = (float*)outp;
                    po[m * Nout + n] = v + res[m * Nout + n];
                } else if (EPI == 2) {
                    float u = 0.7978845608028654f * (v + 0.044715f * v * v * v);
                    u = fminf(fmaxf(u, -10.0f), 10.0f);
                    const float e = __expf(2.0f * u);
                    const float t = (e - 1.0f) / (e + 1.0f);
                    ((bf16_t*)outp)[m * Nout + n] = (bf16_t)(0.5f * v * (1.0f + t));
                } else {
                    if (n < Nout) ((float*)outp)[m * Nout + n] = v;
                }
            }
        }
    }
}

// ------------------------------------------------------------------ launch
extern "C" void kernel_launch(void* const* d_in, const int* in_sizes, int n_in,
                              void* d_out, int out_size, void* d_ws, size_t ws_size,
                              hipStream_t stream) {
    const int*   idx   = (const int*)d_in[0];
    const float* wte   = (const float*)d_in[1];
    const float* wpe   = (const float*)d_in[2];
    const float* ln1_g = (const float*)d_in[3];
    const float* ln1_b = (const float*)d_in[4];
    const float* wqkv  = (const float*)d_in[5];
    const float* bqkv  = (const float*)d_in[6];
    const float* wproj = (const float*)d_in[7];
    const float* bproj = (const float*)d_in[8];
    const float* ln2_g = (const float*)d_in[9];
    const float* ln2_b = (const float*)d_in[10];
    const float* wfc   = (const float*)d_in[11];
    const float* bfc   = (const float*)d_in[12];
    const float* wfc2  = (const float*)d_in[13];
    const float* bfc2  = (const float*)d_in[14];
    const float* lnf_g = (const float*)d_in[15];
    const float* lnf_b = (const float*)d_in[16];
    const float* lm_w  = (const float*)d_in[17];

    char* ws = (char*)d_ws;
    size_t off = 0;
    float*  x      = (float*)(ws + off);  off += (size_t)ROWS * CDIM * 4;
    bf16_t* hbuf   = (bf16_t*)(ws + off); off += (size_t)ROWS * CDIM * 2;
    bf16_t* qkvb   = (bf16_t*)(ws + off); off += (size_t)ROWS * 3 * CDIM * 2;
    bf16_t* vT     = (bf16_t*)(ws + off); off += (size_t)BATCH * NHEAD * 64 * TSEQ * 2;
    bf16_t* yb     = (bf16_t*)(ws + off); off += (size_t)ROWS * CDIM * 2;
    bf16_t* ab     = (bf16_t*)(ws + off); off += (size_t)ROWS * 4 * CDIM * 2;
    bf16_t* wqkvT  = (bf16_t*)(ws + off); off += (size_t)3 * CDIM * CDIM * 2;
    bf16_t* wprojT = (bf16_t*)(ws + off); off += (size_t)CDIM * CDIM * 2;
    bf16_t* wfcT   = (bf16_t*)(ws + off); off += (size_t)4 * CDIM * CDIM * 2;
    bf16_t* wfc2T  = (bf16_t*)(ws + off); off += (size_t)4 * CDIM * CDIM * 2;
    bf16_t* lmwT   = (bf16_t*)(ws + off); off += (size_t)VPAD * CDIM * 2;

    const dim3 tblk(32, 8);

    embed_kernel<<<ROWS, 256, 0, stream>>>(idx, wte, wpe, x);
    // lm_w [768, 50257] -> lmwT [50304, 768] (pad rows zeroed)
    transpose_cvt<<<dim3(VPAD / 32, CDIM / 32), tblk, 0, stream>>>(lm_w, lmwT, CDIM, VOCAB);

    for (int l = 0; l < NLAYER; l++) {
        // all 4 weight transposes of this layer in ONE launch (6912 blocks)
        transpose_layer<<<6912, tblk, 0, stream>>>(
            wqkv + (size_t)l * CDIM * 3 * CDIM, wproj + (size_t)l * CDIM * CDIM,
            wfc + (size_t)l * CDIM * 4 * CDIM,  wfc2 + (size_t)l * 4 * CDIM * CDIM,
            wqkvT, wprojT, wfcT, wfc2T);

        ln_kernel<<<ROWS, 256, 0, stream>>>(x, ln1_g + l * CDIM, ln1_b + l * CDIM, hbuf);
        gemm_bt<0><<<dim3(18, 16), 256, 0, stream>>>(hbuf, wqkvT, bqkv + (size_t)l * 3 * CDIM,
                                                     nullptr, qkvb, CDIM, 3 * CDIM);
        vtrans_kernel<<<dim3(32, 2, BATCH * NHEAD), tblk, 0, stream>>>(qkvb, vT);
        attn_kernel<<<dim3(TSEQ / 64, NHEAD, BATCH), 256, 0, stream>>>(qkvb, vT, yb);
        gemm_bt<1><<<dim3(6, 16), 256, 0, stream>>>(yb, wprojT, bproj + (size_t)l * CDIM,
                                                    x, x, CDIM, CDIM);
        ln_kernel<<<ROWS, 256, 0, stream>>>(x, ln2_g + l * CDIM, ln2_b + l * CDIM, hbuf);
        gemm_bt<2><<<dim3(24, 16), 256, 0, stream>>>(hbuf, wfcT, bfc + (size_t)l * 4 * CDIM,
                                                     nullptr, ab, CDIM, 4 * CDIM);
        gemm_bt<1><<<dim3(6, 16), 256, 0, stream>>>(ab, wfc2T, bfc2 + (size_t)l * CDIM,
                                                    x, x, 4 * CDIM, CDIM);
    }

    ln_kernel<<<ROWS, 256, 0, stream>>>(x, lnf_g, lnf_b, hbuf);
    gemm_bt<3><<<dim3(VPAD / 128, 16), 256, 0, stream>>>(hbuf, lmwT, nullptr, nullptr,
                                                         d_out, CDIM, VOCAB);
}